// Round 1
// baseline (255.633 us; speedup 1.0000x reference)
//
#include <hip/hip_runtime.h>
#include <hip/hip_bf16.h>

#define BB 8
#define LL 4096
#define NCH 8192
#define IDIM 256
#define KDIM 512
#define ODIM 512
#define NDIR 6
#define TOT (BB * LL)  // 32768

typedef short short8 __attribute__((ext_vector_type(8)));
typedef float floatx4 __attribute__((ext_vector_type(4)));

// ws layout:
//   ints [0..7]   cnt per dir
//   ints [8..15]  fill cursors
//   ints [64 .. 64+TOT)        idx  (lin per bucketed row)
//   ints [64+TOT .. 64+2*TOT)  rows (r0 | r1<<16)
//   then bf16 W copy (3 MB). `last` stays f32 in its input buffer (no copy).
#define WS_W_OFF (64 + 2 * TOT)
#define W_ELEMS (NDIR * ODIM * KDIM)  // 1,572,864
#define N_W8 (W_ELEMS / 8)            // 196,608

// gemm grid: 4 n-tiles x 262 m-tiles = 1048 blocks = 8 * 131 (bijective XCD swizzle)
#define GEMM_NWG 1048
#define GEMM_CHUNK 131

__device__ inline void cvt8(const float* __restrict__ src,
                            __hip_bfloat16* __restrict__ dst, int i) {
  const floatx4* s = (const floatx4*)src;
  floatx4 a = s[2 * i];
  floatx4 b = s[2 * i + 1];
  union { short8 v; __hip_bfloat16 h[8]; } u;
  u.h[0] = __float2bfloat16(a[0]); u.h[1] = __float2bfloat16(a[1]);
  u.h[2] = __float2bfloat16(a[2]); u.h[3] = __float2bfloat16(a[3]);
  u.h[4] = __float2bfloat16(b[0]); u.h[5] = __float2bfloat16(b[1]);
  u.h[6] = __float2bfloat16(b[2]); u.h[7] = __float2bfloat16(b[3]);
  ((short8*)dst)[i] = u.v;
}

// ---- prep: cvt(W) + dir histogram, fused (homogeneous 256-blocks) ----
__global__ __launch_bounds__(256) void prep_kernel(
    const float* __restrict__ W, const int* __restrict__ vec,
    const int* __restrict__ dmap, int* __restrict__ ws) {
  __hip_bfloat16* W_bf = (__hip_bfloat16*)(ws + WS_W_OFF);
  int gid = blockIdx.x * 256 + threadIdx.x;
  if (gid < N_W8) {
    cvt8(W, W_bf, gid);
  } else {
    __shared__ int lcnt[8];
    int tid = threadIdx.x;
    if (tid < 8) lcnt[tid] = 0;
    __syncthreads();
    int lin = gid - N_W8;
    int dir = dmap[vec[lin]] & 7;
    atomicAdd(&lcnt[dir], 1);
    __syncthreads();
    if (tid < 8 && lcnt[tid]) atomicAdd(&ws[tid], lcnt[tid]);
  }
}

// ---- scatter into compact buckets (computes its own 8-entry scan) ----
__global__ __launch_bounds__(256) void scatter_kernel(
    const int* __restrict__ vec, const int* __restrict__ child_l,
    const int* __restrict__ child_r, const int* __restrict__ drev,
    const int* __restrict__ dmap, int* __restrict__ ws) {
  __shared__ int lcnt[8];
  __shared__ int gbase[8];
  __shared__ int baseS[8];
  int* fill = ws + 8;
  int* idx = ws + 64;
  int* rows = ws + 64 + TOT;

  int tid = threadIdx.x;
  if (tid < 8) {
    lcnt[tid] = 0;
    int s = 0;
    for (int i = 0; i < tid; ++i) s += ws[i];  // exclusive scan of counts
    baseS[tid] = s;
  }
  __syncthreads();

  int lin = blockIdx.x * 256 + tid;
  int l = lin & (LL - 1);
  int v = vec[lin];
  int dir = dmap[v] & 7;
  int sw = drev[v];
  int cl = child_l[l];
  int cr = child_r[l];
  int r0 = sw ? cr : cl;
  int r1 = sw ? cl : cr;
  int pos = atomicAdd(&lcnt[dir], 1);
  __syncthreads();
  if (tid < 8) gbase[tid] = lcnt[tid] ? atomicAdd(&fill[tid], lcnt[tid]) : 0;
  __syncthreads();
  int slot = baseS[dir] + gbase[dir] + pos;
  idx[slot] = lin;
  rows[slot] = r0 | (r1 << 16);
}

// ---- grouped GEMM: 128x128 tile, NO LDS, NO barriers ----
// 4 waves (2x2), each wave 64x64 via 4x4 mfma_f32_16x16x32_bf16.
// A is read directly from f32 `last` (gathered rows) and converted in-register;
// B (W) is read as bf16 from the ws copy (L2-resident, 3 MB).
// 16 pipeline steps of K=32, register double-buffered, issue-one-ahead.
__global__ __launch_bounds__(256, 2) void gemm_kernel(
    const float* __restrict__ last, const float* __restrict__ bias,
    const float* __restrict__ alpha_m, const int* __restrict__ ws,
    float* __restrict__ out) {
  // ---- bijective XCD swizzle: consecutive-dispatch blocks -> same XCD chunk,
  //      so the 4 n-tiles of neighboring m-tiles share one XCD's L2 for A.
  int flat = blockIdx.y * 4 + blockIdx.x;           // dispatch order (x fastest)
  int swz = (flat & 7) * GEMM_CHUNK + (flat >> 3);  // 1048 = 8*131 exactly
  const int mt = swz >> 2;
  const int nt = swz & 3;

  // ---- tile -> dir mapping (computes prefix locally; no scan kernel) ----
  int d = -1, count = 0, off = 0, m_base = 0;
  {
    int tb = 0, run = 0;
    for (int dd = 0; dd < NDIR; ++dd) {
      int c = ws[dd];
      int ntile = (c + 127) >> 7;
      if (mt < tb + ntile) { d = dd; count = c; off = run; m_base = (mt - tb) * 128; break; }
      tb += ntile; run += c;
    }
  }
  if (d < 0) return;

  const int* idx = ws + 64;
  const int* rows = ws + 64 + TOT;
  const char* W_bf = (const char*)(ws + WS_W_OFF);
  const char* lastc = (const char*)last;

  const int tid = threadIdx.x;
  const int wave = __builtin_amdgcn_readfirstlane(tid >> 6);
  const int lane = tid & 63;
  const int lane15 = lane & 15;
  const int quad = lane >> 4;
  const int wm = wave >> 1;
  const int wn = wave & 1;
  const int n_blk = nt * 128;

  // ---- per-lane gathered A row byte-offsets (4 frag-rows x {r0, r1}) ----
  int aoff0[4], aoff1[4];
#pragma unroll
  for (int i = 0; i < 4; ++i) {
    int lr = m_base + wm * 64 + i * 16 + lane15;
    if (lr >= count) lr = count - 1;  // clamp (tile exists => count>0)
    int lin = idx[off + lr] & (TOT - 1);
    int rr = rows[off + lr];
    int b = lin >> 12;
    aoff0[i] = ((b * NCH + (rr & (NCH - 1))) * IDIM + quad * 8) * 4;
    aoff1[i] = ((b * NCH + ((rr >> 16) & (NCH - 1))) * IDIM + quad * 8) * 4;
  }
  // ---- B (W row) byte-offsets ----
  int boff[4];
#pragma unroll
  for (int j = 0; j < 4; ++j)
    boff[j] = ((d * ODIM + n_blk + wn * 64 + j * 16 + lane15) * KDIM + quad * 8) * 2;

  floatx4 acc[4][4] = {};
  floatx4 pA[2][4][2];  // [buf][frag][lo/hi] f32 prefetch
  short8 pB[2][4];      // [buf][frag] bf16

  // prologue: issue step 0 (kt=0, s=0, half=r0)
#pragma unroll
  for (int i = 0; i < 4; ++i) {
    const char* p = lastc + aoff0[i];
    pA[0][i][0] = *(const floatx4*)p;
    pA[0][i][1] = *(const floatx4*)(p + 16);
  }
#pragma unroll
  for (int j = 0; j < 4; ++j)
    pB[0][j] = *(const short8*)(W_bf + boff[j]);

  // 16 steps: step t covers global k-cols [t*32, t*32+32)
#pragma unroll
  for (int t = 0; t < 16; ++t) {
    const int cur = t & 1, nxt = cur ^ 1;
    if (t < 15) {
      const int tn = t + 1;
      const int half = tn >> 3;                            // 0: r0 cols, 1: r1 cols
      const int cA = (((tn >> 1) & 3) * 64 + (tn & 1) * 32) * 4;  // bytes in source row
#pragma unroll
      for (int i = 0; i < 4; ++i) {
        const char* p = lastc + (half ? aoff1[i] : aoff0[i]) + cA;
        pA[nxt][i][0] = *(const floatx4*)p;
        pA[nxt][i][1] = *(const floatx4*)(p + 16);
      }
      const int cB = tn * 32 * 2;  // bytes in W row
#pragma unroll
      for (int j = 0; j < 4; ++j)
        pB[nxt][j] = *(const short8*)(W_bf + boff[j] + cB);
    }
    short8 a[4];
#pragma unroll
    for (int i = 0; i < 4; ++i) {
      const floatx4 lo = pA[cur][i][0];
      const floatx4 hi = pA[cur][i][1];
      union { short8 v; __hip_bfloat16 h[8]; } u;
      u.h[0] = __float2bfloat16(lo[0]); u.h[1] = __float2bfloat16(lo[1]);
      u.h[2] = __float2bfloat16(lo[2]); u.h[3] = __float2bfloat16(lo[3]);
      u.h[4] = __float2bfloat16(hi[0]); u.h[5] = __float2bfloat16(hi[1]);
      u.h[6] = __float2bfloat16(hi[2]); u.h[7] = __float2bfloat16(hi[3]);
      a[i] = u.v;
    }
#pragma unroll
    for (int i = 0; i < 4; ++i)
#pragma unroll
      for (int j = 0; j < 4; ++j)
        acc[i][j] = __builtin_amdgcn_mfma_f32_16x16x32_bf16(a[i], pB[cur][j], acc[i][j], 0, 0, 0);
  }

  // ---- epilogue: bias + leaky relu, scatter rows ----
  const float alpha = alpha_m[d];
  float bj[4];
#pragma unroll
  for (int j = 0; j < 4; ++j)
    bj[j] = bias[d * ODIM + n_blk + wn * 64 + j * 16 + lane15];

#pragma unroll
  for (int i = 0; i < 4; ++i) {
#pragma unroll
    for (int reg = 0; reg < 4; ++reg) {
      int row_id = m_base + wm * 64 + i * 16 + quad * 4 + reg;
      if (row_id >= count) continue;
      int lin = idx[off + row_id] & (TOT - 1);
      float* orow = out + (long long)lin * ODIM + n_blk + wn * 64;
#pragma unroll
      for (int j = 0; j < 4; ++j) {
        float y = acc[i][j][reg] + bj[j];
        y = y > 0.f ? y : alpha * y;
        orow[j * 16 + lane15] = y;
      }
    }
  }
}

extern "C" void kernel_launch(void* const* d_in, const int* in_sizes, int n_in,
                              void* d_out, int out_size, void* d_ws, size_t ws_size,
                              hipStream_t stream) {
  const float* last = (const float*)d_in[0];
  const float* W = (const float*)d_in[1];
  const float* bias = (const float*)d_in[2];
  const float* alpha = (const float*)d_in[3];
  const int* child_l = (const int*)d_in[4];
  const int* child_r = (const int*)d_in[5];
  const int* vec = (const int*)d_in[6];
  const int* drev = (const int*)d_in[7];
  const int* dmap = (const int*)d_in[8];

  int* ws = (int*)d_ws;

  hipMemsetAsync(ws, 0, 64 * sizeof(int), stream);
  // prep: W cvt (768 blocks) + histogram (128 blocks); regions 256-divisible
  prep_kernel<<<(N_W8 + TOT) / 256, 256, 0, stream>>>(W, vec, dmap, ws);
  scatter_kernel<<<TOT / 256, 256, 0, stream>>>(vec, child_l, child_r, drev, dmap, ws);
  // max tiles = 256 + (NDIR-1) from per-dir 128-padding -> grid.y = 262
  dim3 grid(ODIM / 128, TOT / 128 + NDIR, 1);
  gemm_kernel<<<grid, 256, 0, stream>>>(last, bias, alpha, ws, (float*)d_out);
}

// Round 2
// 184.217 us; speedup vs baseline: 1.3877x; 1.3877x over previous
//
#include <hip/hip_runtime.h>
#include <hip/hip_bf16.h>

#define BB 8
#define LL 4096
#define NCH 8192
#define IDIM 256
#define KDIM 512
#define ODIM 512
#define NDIR 6
#define TOT (BB * LL)  // 32768

typedef short short8 __attribute__((ext_vector_type(8)));
typedef float floatx4 __attribute__((ext_vector_type(4)));

// ws layout:
//   ints [0..7]   cnt per dir
//   ints [8..15]  fill cursors
//   ints [64 .. 64+TOT)        idx  (lin per bucketed row)
//   ints [64+TOT .. 64+2*TOT)  rows (r0 | r1<<16)
//   then bf16 last copy (33.5 MB), bf16 W copy (3 MB)  => ~37 MB total
#define WS_LAST_OFF (64 + 2 * TOT)
#define LAST_ELEMS (BB * NCH * IDIM)  // 16,777,216
#define W_ELEMS (NDIR * ODIM * KDIM)  // 1,572,864
#define N_LAST8 (LAST_ELEMS / 8)      // 2,097,152
#define N_W8 (W_ELEMS / 8)            // 196,608

// gemm grid: 4 n-tiles x 262 m-tiles = 1048 = 8 * 131 (bijective XCD swizzle)
#define GEMM_CHUNK 131

__device__ inline void async_copy16(const void* g, void* l) {
  __builtin_amdgcn_global_load_lds(
      (const __attribute__((address_space(1))) void*)g,
      (__attribute__((address_space(3))) void*)l, 16, 0, 0);
}

__device__ inline void cvt8(const float* __restrict__ src,
                            __hip_bfloat16* __restrict__ dst, int i) {
  const floatx4* s = (const floatx4*)src;
  floatx4 a = s[2 * i];
  floatx4 b = s[2 * i + 1];
  union { short8 v; __hip_bfloat16 h[8]; } u;
  u.h[0] = __float2bfloat16(a[0]); u.h[1] = __float2bfloat16(a[1]);
  u.h[2] = __float2bfloat16(a[2]); u.h[3] = __float2bfloat16(a[3]);
  u.h[4] = __float2bfloat16(b[0]); u.h[5] = __float2bfloat16(b[1]);
  u.h[6] = __float2bfloat16(b[2]); u.h[7] = __float2bfloat16(b[3]);
  ((short8*)dst)[i] = u.v;
}

// ---- prep: cvt(last) + cvt(W) + dir histogram, fused (homogeneous blocks) ----
__global__ __launch_bounds__(256) void prep_kernel(
    const float* __restrict__ last, const float* __restrict__ W,
    const int* __restrict__ vec, const int* __restrict__ dmap,
    int* __restrict__ ws) {
  __hip_bfloat16* last_bf = (__hip_bfloat16*)(ws + WS_LAST_OFF);
  __hip_bfloat16* W_bf = last_bf + LAST_ELEMS;
  int gid = blockIdx.x * 256 + threadIdx.x;
  if (gid < N_LAST8) {
    cvt8(last, last_bf, gid);
  } else if (gid < N_LAST8 + N_W8) {
    cvt8(W, W_bf, gid - N_LAST8);
  } else {
    __shared__ int lcnt[8];
    int tid = threadIdx.x;
    if (tid < 8) lcnt[tid] = 0;
    __syncthreads();
    int lin = gid - (N_LAST8 + N_W8);
    int dir = dmap[vec[lin]] & 7;
    atomicAdd(&lcnt[dir], 1);
    __syncthreads();
    if (tid < 8 && lcnt[tid]) atomicAdd(&ws[tid], lcnt[tid]);
  }
}

// ---- scatter into compact buckets (computes its own 8-entry scan) ----
__global__ __launch_bounds__(256) void scatter_kernel(
    const int* __restrict__ vec, const int* __restrict__ child_l,
    const int* __restrict__ child_r, const int* __restrict__ drev,
    const int* __restrict__ dmap, int* __restrict__ ws) {
  __shared__ int lcnt[8];
  __shared__ int gbase[8];
  __shared__ int baseS[8];
  int* fill = ws + 8;
  int* idx = ws + 64;
  int* rows = ws + 64 + TOT;

  int tid = threadIdx.x;
  if (tid < 8) {
    lcnt[tid] = 0;
    int s = 0;
    for (int i = 0; i < tid; ++i) s += ws[i];  // exclusive scan of counts
    baseS[tid] = s;
  }
  __syncthreads();

  int lin = blockIdx.x * 256 + tid;
  int l = lin & (LL - 1);
  int v = vec[lin];
  int dir = dmap[v] & 7;
  int sw = drev[v];
  int cl = child_l[l];
  int cr = child_r[l];
  int r0 = sw ? cr : cl;
  int r1 = sw ? cl : cr;
  int pos = atomicAdd(&lcnt[dir], 1);
  __syncthreads();
  if (tid < 8) gbase[tid] = lcnt[tid] ? atomicAdd(&fill[tid], lcnt[tid]) : 0;
  __syncthreads();
  int slot = baseS[dir] + gbase[dir] + pos;
  idx[slot] = lin;
  rows[slot] = r0 | (r1 << 16);
}

// ---- grouped GEMM: 128x128 tile, BK=64, double-buffered A in LDS,
//      B read directly from L2-resident bf16 W copy (no B LDS).
// Block = 4 waves (2x2), each wave 64x64 via 4x4 mfma_f32_16x16x32_bf16.
// Pipeline: per K-step issue next A-stage (global_load_lds) BEFORE computing
// the current buffer; ONE barrier per step (compiler drains vmcnt before it),
// so stage latency hides under B-loads + 32 MFMAs.
__global__ __launch_bounds__(256) void gemm_kernel(
    const float* __restrict__ bias, const float* __restrict__ alpha_m,
    const int* __restrict__ ws, float* __restrict__ out) {
  __shared__ __hip_bfloat16 Als[2][128 * 64];  // 2 x 16 KB

  // bijective XCD swizzle: the 4 n-tiles of neighboring m-tiles share one
  // XCD's L2 for the gathered A panels (1048 = 8*131 exactly).
  int flat = blockIdx.y * 4 + blockIdx.x;           // dispatch order (x fastest)
  int swz = (flat & 7) * GEMM_CHUNK + (flat >> 3);
  const int mt = swz >> 2;
  const int nt = swz & 3;

  // ---- tile -> dir mapping (local prefix; no scan kernel) ----
  int d = -1, count = 0, off = 0, m_base = 0;
  {
    int tb = 0, run = 0;
    for (int dd = 0; dd < NDIR; ++dd) {
      int c = ws[dd];
      int ntile = (c + 127) >> 7;
      if (mt < tb + ntile) { d = dd; count = c; off = run; m_base = (mt - tb) * 128; break; }
      tb += ntile; run += c;
    }
  }
  if (d < 0) return;

  const int* idx = ws + 64;
  const int* rows = ws + 64 + TOT;
  const __hip_bfloat16* last_bf = (const __hip_bfloat16*)(ws + WS_LAST_OFF);
  const __hip_bfloat16* W_bf = last_bf + LAST_ELEMS;

  const int tid = threadIdx.x;
  const int wave = __builtin_amdgcn_readfirstlane(tid >> 6);
  const int lane = tid & 63;
  const int lane15 = lane & 15;
  const int quad = lane >> 4;
  const int wm = wave >> 1;
  const int wn = wave & 1;
  const int n_blk = nt * 128;

  // ---- A staging descriptors: per wave 4 instrs, 8 rows each ----
  const __hip_bfloat16* ap0[4];
  const __hip_bfloat16* ap1[4];
  int ldsrow[4];
#pragma unroll
  for (int i = 0; i < 4; ++i) {
    int sr = wave * 32 + i * 8 + (lane >> 3);  // local row 0..127
    ldsrow[i] = (wave * 32 + i * 8) * 64;      // lds elem offset (wave-uniform)
    int lr = m_base + sr;
    if (lr >= count) lr = count - 1;  // clamp (tile exists => count>0)
    int lin = idx[off + lr] & (TOT - 1);
    int rr = rows[off + lr];
    int b = lin >> 12;
    int r0 = rr & (NCH - 1);
    int r1 = (rr >> 16) & (NCH - 1);
    int xu = ((lane & 7) ^ (sr & 7)) * 8;  // swizzled 16B-unit -> elems
    ap0[i] = last_bf + (long long)(b * NCH + r0) * IDIM + xu;
    ap1[i] = last_bf + (long long)(b * NCH + r1) * IDIM + xu;
  }
  // ---- B fragment base pointers (direct global reads, L2-hot 3 MB) ----
  const __hip_bfloat16* bp[4];
#pragma unroll
  for (int j = 0; j < 4; ++j)
    bp[j] = W_bf + (long long)(d * ODIM + n_blk + wn * 64 + j * 16 + lane15) * KDIM + quad * 8;

  floatx4 acc[4][4] = {};
  const int lx = lane15 & 7;  // frag-read swizzle key (row&7 == lane15&7)

  // prologue: stage kt=0 into buf 0
#pragma unroll
  for (int i = 0; i < 4; ++i) async_copy16(ap0[i], &Als[0][ldsrow[i]]);
  __syncthreads();

#pragma unroll
  for (int kt = 0; kt < 8; ++kt) {
    const int cur = kt & 1;
    // B fragment loads for this step (issued before the stage so their
    // vmcnt waits don't force draining the stage).
    short8 bfr[2][4];
#pragma unroll
    for (int s = 0; s < 2; ++s)
#pragma unroll
      for (int j = 0; j < 4; ++j)
        bfr[s][j] = *(const short8*)(bp[j] + kt * 64 + s * 32);

    // issue next A-stage into the other buffer
    if (kt < 7) {
      const int tn = kt + 1;
      const int ko = (tn & 3) * 64;
#pragma unroll
      for (int i = 0; i < 4; ++i) {
        const __hip_bfloat16* ga = (tn < 4 ? ap0[i] : ap1[i]) + ko;
        async_copy16(ga, &Als[cur ^ 1][ldsrow[i]]);
      }
    }

    // compute current buffer
#pragma unroll
    for (int s = 0; s < 2; ++s) {
      const int xcol = ((quad + 4 * s) ^ lx) * 8;  // swizzled elem offset
      short8 a[4];
#pragma unroll
      for (int i = 0; i < 4; ++i)
        a[i] = *(const short8*)&Als[cur][(wm * 64 + i * 16 + lane15) * 64 + xcol];
#pragma unroll
      for (int i = 0; i < 4; ++i)
#pragma unroll
        for (int j = 0; j < 4; ++j)
          acc[i][j] = __builtin_amdgcn_mfma_f32_16x16x32_bf16(a[i], bfr[s][j], acc[i][j], 0, 0, 0);
    }
    __syncthreads();  // next-buffer staging visible; current reads complete
  }

  // ---- epilogue: bias + leaky relu, scatter rows ----
  const float alpha = alpha_m[d];
  float bj[4];
#pragma unroll
  for (int j = 0; j < 4; ++j)
    bj[j] = bias[d * ODIM + n_blk + wn * 64 + j * 16 + lane15];

#pragma unroll
  for (int i = 0; i < 4; ++i) {
#pragma unroll
    for (int reg = 0; reg < 4; ++reg) {
      int row_id = m_base + wm * 64 + i * 16 + quad * 4 + reg;
      if (row_id >= count) continue;
      int lin = idx[off + row_id] & (TOT - 1);
      float* orow = out + (long long)lin * ODIM + n_blk + wn * 64;
#pragma unroll
      for (int j = 0; j < 4; ++j) {
        float y = acc[i][j][reg] + bj[j];
        y = y > 0.f ? y : alpha * y;
        orow[j * 16 + lane15] = y;
      }
    }
  }
}

extern "C" void kernel_launch(void* const* d_in, const int* in_sizes, int n_in,
                              void* d_out, int out_size, void* d_ws, size_t ws_size,
                              hipStream_t stream) {
  const float* last = (const float*)d_in[0];
  const float* W = (const float*)d_in[1];
  const float* bias = (const float*)d_in[2];
  const float* alpha = (const float*)d_in[3];
  const int* child_l = (const int*)d_in[4];
  const int* child_r = (const int*)d_in[5];
  const int* vec = (const int*)d_in[6];
  const int* drev = (const int*)d_in[7];
  const int* dmap = (const int*)d_in[8];

  int* ws = (int*)d_ws;

  hipMemsetAsync(ws, 0, 64 * sizeof(int), stream);
  int prep_blocks = (N_LAST8 + N_W8 + TOT) / 256;  // all regions 256-divisible
  prep_kernel<<<prep_blocks, 256, 0, stream>>>(last, W, vec, dmap, ws);
  scatter_kernel<<<TOT / 256, 256, 0, stream>>>(vec, child_l, child_r, drev, dmap, ws);
  // max tiles = 256 + (NDIR-1) from per-dir 128-padding -> grid.y = 262
  dim3 grid(ODIM / 128, TOT / 128 + NDIR, 1);
  gemm_kernel<<<grid, 256, 0, stream>>>(bias, alpha, ws, (float*)d_out);
}

// Round 3
// 182.838 us; speedup vs baseline: 1.3981x; 1.0075x over previous
//
#include <hip/hip_runtime.h>
#include <hip/hip_bf16.h>

#define BB 8
#define LL 4096
#define NCH 8192
#define IDIM 256
#define KDIM 512
#define ODIM 512
#define NDIR 6
#define TOT (BB * LL)  // 32768

// Per-dir bucket capacity. Expected count = TOT/6 ~= 5461 (sigma ~150 for the
// fixed input seed); 8192 gives ~18-sigma headroom and keeps ws compact.
#define CAP 8192
#define IDX_OFF 64
#define ROWS_OFF (64 + 8 * CAP)
#define WS_LAST_OFF (64 + 16 * CAP)
#define LAST_ELEMS (BB * NCH * IDIM)  // 16,777,216
#define W_ELEMS (NDIR * ODIM * KDIM)  // 1,572,864
#define N_LAST8 (LAST_ELEMS / 8)      // 2,097,152 -> 8192 blocks
#define N_W8 (W_ELEMS / 8)            // 196,608  -> 768 blocks

// gemm grid: 8 n-tiles x 518 m-tiles = 4144 = 8 * 518 (bijective XCD swizzle)
#define MTILES (TOT / 64 + NDIR)  // 518
typedef short short8 __attribute__((ext_vector_type(8)));
typedef float floatx4 __attribute__((ext_vector_type(4)));

__device__ inline void async_copy16(const void* g, void* l) {
  __builtin_amdgcn_global_load_lds(
      (const __attribute__((address_space(1))) void*)g,
      (__attribute__((address_space(3))) void*)l, 16, 0, 0);
}

__device__ inline void cvt8(const float* __restrict__ src,
                            __hip_bfloat16* __restrict__ dst, int i) {
  const floatx4* s = (const floatx4*)src;
  floatx4 a = s[2 * i];
  floatx4 b = s[2 * i + 1];
  union { short8 v; __hip_bfloat16 h[8]; } u;
  u.h[0] = __float2bfloat16(a[0]); u.h[1] = __float2bfloat16(a[1]);
  u.h[2] = __float2bfloat16(a[2]); u.h[3] = __float2bfloat16(a[3]);
  u.h[4] = __float2bfloat16(b[0]); u.h[5] = __float2bfloat16(b[1]);
  u.h[6] = __float2bfloat16(b[2]); u.h[7] = __float2bfloat16(b[3]);
  ((short8*)dst)[i] = u.v;
}

// ---- fused prep: cvt(last) + cvt(W) + scatter into fixed-cap buckets ----
// (no histogram/scan pass: buckets are CAP-strided, counts = fill cursors)
__global__ __launch_bounds__(256) void prep_kernel(
    const float* __restrict__ last, const float* __restrict__ W,
    const int* __restrict__ vec, const int* __restrict__ child_l,
    const int* __restrict__ child_r, const int* __restrict__ drev,
    const int* __restrict__ dmap, int* __restrict__ ws) {
  __hip_bfloat16* last_bf = (__hip_bfloat16*)(ws + WS_LAST_OFF);
  __hip_bfloat16* W_bf = last_bf + LAST_ELEMS;
  int gid = blockIdx.x * 256 + threadIdx.x;
  if (gid < N_LAST8) {
    cvt8(last, last_bf, gid);
  } else if (gid < N_LAST8 + N_W8) {
    cvt8(W, W_bf, gid - N_LAST8);
  } else {
    __shared__ int lcnt[8];
    __shared__ int gbase[8];
    int tid = threadIdx.x;
    if (tid < 8) lcnt[tid] = 0;
    __syncthreads();
    int lin = gid - (N_LAST8 + N_W8);
    int l = lin & (LL - 1);
    int v = vec[lin];
    int dir = dmap[v] & 7;
    int sw = drev[v];
    int cl = child_l[l];
    int cr = child_r[l];
    int r0 = sw ? cr : cl;
    int r1 = sw ? cl : cr;
    int pos = atomicAdd(&lcnt[dir], 1);
    __syncthreads();
    if (tid < 8) gbase[tid] = lcnt[tid] ? atomicAdd(&ws[tid], lcnt[tid]) : 0;
    __syncthreads();
    int slot = dir * CAP + gbase[dir] + pos;
    ws[IDX_OFF + slot] = lin;
    ws[ROWS_OFF + slot] = r0 | (r1 << 16);
  }
}

// ---- grouped GEMM: 1 wave / block, 64x64 tile, ZERO barriers ----
// Private 2 x 8KB LDS double buffer per wave; counted s_waitcnt vmcnt(8)
// keeps the next A-stage (8 global_load_lds) in flight across the compute.
// B read directly from the L2-resident bf16 W copy. Waves self-pace; ~10
// independent streams/CU hide residual gather latency.
__global__ __launch_bounds__(64) void gemm_kernel(
    const float* __restrict__ bias, const float* __restrict__ alpha_m,
    const int* __restrict__ ws, float* __restrict__ out) {
  __shared__ __hip_bfloat16 Als[2][64 * 64];  // 2 x 8 KB

  // bijective XCD swizzle (4144 = 8*518): each XCD gets ~65 consecutive
  // m-tiles with all 8 n-tiles adjacent -> A panel reused x8 from its L2.
  int flat = blockIdx.y * 8 + blockIdx.x;  // dispatch order (x fastest)
  int swz = (flat & 7) * MTILES + (flat >> 3);
  const int mt = swz >> 3;
  const int nt = swz & 7;

  // ---- tile -> dir mapping (counts = fill cursors at ws[0..7]) ----
  int d = -1, count = 0, m_base = 0;
  {
    int tb = 0;
    for (int dd = 0; dd < 8; ++dd) {
      int c = ws[dd];
      int ntile = (c + 63) >> 6;
      if (mt < tb + ntile) { d = dd; count = c; m_base = (mt - tb) * 64; break; }
      tb += ntile;
    }
  }
  if (d < 0) return;

  const int* idxA = ws + IDX_OFF + d * CAP;
  const int* rowsA = ws + ROWS_OFF + d * CAP;
  const char* last_bf = (const char*)(ws + WS_LAST_OFF);
  const char* W_bf = last_bf + (long long)LAST_ELEMS * 2;

  const int lane = threadIdx.x;  // 0..63 (one wave)
  const int lane15 = lane & 15;
  const int quad = lane >> 4;

  // ---- A staging descriptors: 8 instrs, 8 rows each (row = lane>>3) ----
  // XOR-swizzle 16B units by row&7 on the global side; LDS stays linear.
  int aoff0[8], aoff1[8];
  const int xu2 = (((lane & 7) ^ (lane >> 3)) * 8) * 2;  // byte off in row
#pragma unroll
  for (int i = 0; i < 8; ++i) {
    int gr = m_base + i * 8 + (lane >> 3);
    if (gr >= count) gr = count - 1;  // clamp (tile exists => count>0)
    int lin = idxA[gr] & (TOT - 1);
    int rr = rowsA[gr];
    int b = lin >> 12;
    aoff0[i] = (b * NCH + (rr & (NCH - 1))) * (IDIM * 2) + xu2;
    aoff1[i] = (b * NCH + ((rr >> 16) & (NCH - 1))) * (IDIM * 2) + xu2;
  }
  // ---- B fragment byte-offsets (direct global reads, L2-hot 3 MB) ----
  int boff[4];
#pragma unroll
  for (int j = 0; j < 4; ++j)
    boff[j] = ((d * ODIM + nt * 64 + j * 16 + lane15) * KDIM + quad * 8) * 2;

  floatx4 acc[4][4] = {};
  const int lx = lane15 & 7;  // frag-read swizzle key

  // prologue: stage t=0 into buf 0
#pragma unroll
  for (int i = 0; i < 8; ++i)
    async_copy16(last_bf + aoff0[i], &Als[0][i * 512]);

#pragma unroll
  for (int t = 0; t < 8; ++t) {
    const int cur = t & 1;
    // B loads for THIS step, issued BEFORE the next stage so the counted
    // vmcnt(8) (8 = the stage just issued) also covers them. FIFO vmcnt.
    short8 bfr[2][4];
#pragma unroll
    for (int s = 0; s < 2; ++s)
#pragma unroll
      for (int j = 0; j < 4; ++j)
        bfr[s][j] = *(const short8*)(W_bf + boff[j] + (t * 64 + s * 32) * 2);

    // WAR guard: previous-step ds_reads of buf[cur^1] must have landed
    // before we overwrite it (lgkm already drained by MFMA consumption;
    // this is ~free but makes the ordering architectural).
    asm volatile("s_waitcnt lgkmcnt(0)" ::: "memory");
    if (t < 7) {
      const int tn = t + 1;
      const int ko = (tn & 3) * (64 * 2);
#pragma unroll
      for (int i = 0; i < 8; ++i)
        async_copy16(last_bf + (tn < 4 ? aoff0[i] : aoff1[i]) + ko,
                     &Als[cur ^ 1][i * 512]);
      asm volatile("s_waitcnt vmcnt(8)" ::: "memory");  // stage(t)+B(t) done
    } else {
      asm volatile("s_waitcnt vmcnt(0)" ::: "memory");
    }
    __builtin_amdgcn_sched_barrier(0);

#pragma unroll
    for (int s = 0; s < 2; ++s) {
      const int xcol = ((quad + 4 * s) ^ lx) * 8;  // swizzled elem offset
      short8 a[4];
#pragma unroll
      for (int i = 0; i < 4; ++i)
        a[i] = *(const short8*)&Als[cur][(i * 16 + lane15) * 64 + xcol];
#pragma unroll
      for (int i = 0; i < 4; ++i)
#pragma unroll
        for (int j = 0; j < 4; ++j)
          acc[i][j] = __builtin_amdgcn_mfma_f32_16x16x32_bf16(a[i], bfr[s][j], acc[i][j], 0, 0, 0);
    }
  }

  // ---- epilogue: bias + leaky relu, scatter rows ----
  const float alpha = alpha_m[d];
  float bj[4];
#pragma unroll
  for (int j = 0; j < 4; ++j)
    bj[j] = bias[d * ODIM + nt * 64 + j * 16 + lane15];

#pragma unroll
  for (int i = 0; i < 4; ++i) {
#pragma unroll
    for (int reg = 0; reg < 4; ++reg) {
      int row_id = m_base + i * 16 + quad * 4 + reg;
      if (row_id >= count) continue;
      int lin = idxA[row_id] & (TOT - 1);
      float* orow = out + (long long)lin * ODIM + nt * 64;
#pragma unroll
      for (int j = 0; j < 4; ++j) {
        float y = acc[i][j][reg] + bj[j];
        y = y > 0.f ? y : alpha * y;
        orow[j * 16 + lane15] = y;
      }
    }
  }
}

extern "C" void kernel_launch(void* const* d_in, const int* in_sizes, int n_in,
                              void* d_out, int out_size, void* d_ws, size_t ws_size,
                              hipStream_t stream) {
  const float* last = (const float*)d_in[0];
  const float* W = (const float*)d_in[1];
  const float* bias = (const float*)d_in[2];
  const float* alpha = (const float*)d_in[3];
  const int* child_l = (const int*)d_in[4];
  const int* child_r = (const int*)d_in[5];
  const int* vec = (const int*)d_in[6];
  const int* drev = (const int*)d_in[7];
  const int* dmap = (const int*)d_in[8];

  int* ws = (int*)d_ws;

  hipMemsetAsync(ws, 0, 64 * sizeof(int), stream);
  // fused prep: last-cvt (8192 blocks) + W-cvt (768) + scatter (128)
  int prep_blocks = N_LAST8 / 256 + N_W8 / 256 + TOT / 256;
  prep_kernel<<<prep_blocks, 256, 0, stream>>>(last, W, vec, child_l, child_r,
                                               drev, dmap, ws);
  dim3 grid(8, MTILES, 1);  // 4144 blocks, 64 threads each
  gemm_kernel<<<grid, 64, 0, stream>>>(bias, alpha, ws, (float*)d_out);
}